// Round 16
// baseline (105.211 us; speedup 1.0000x reference)
//
#include <hip/hip_runtime.h>
#include <hip/hip_bf16.h>
#include <math.h>

#define NB 4
#define NS 2048
#define ND 256
#define NH 8
#define NDK 32
#define NDFF 1024
#define NROWS (NB * NS)   // 8192
#define KC 4              // split-K chunks in attention
#define KVB 128
#define KTILES (NS / KC / KVB)  // 4
#define QVLD 384          // fused qkv output row stride

using short8 = __attribute__((ext_vector_type(8))) short;
using f32x4  = __attribute__((ext_vector_type(4))) float;

__device__ __forceinline__ unsigned short f2bf(float f) {
  union { float f; unsigned u; } v; v.f = f;
  unsigned r = v.u + 0x7fffu + ((v.u >> 16) & 1u);
  return (unsigned short)(r >> 16);
}
__device__ __forceinline__ float bf2f(unsigned short u) {
  union { unsigned u; float f; } v; v.u = ((unsigned)u) << 16;
  return v.f;
}
__device__ __forceinline__ unsigned cvt_pk_bf16(float lo, float hi) {
  unsigned r;
  asm("v_cvt_pk_bf16_f32 %0, %1, %2" : "=v"(r) : "v"(lo), "v"(hi));
  return r;
}
// async global->LDS, 16B per lane; dest must be wave-uniform base + lane*16
__device__ __forceinline__ void gl_lds16(const void* g, void* l) {
  __builtin_amdgcn_global_load_lds(
      (const __attribute__((address_space(1))) unsigned int*)g,
      (__attribute__((address_space(3))) unsigned int*)l, 16, 0, 0);
}
// f32x8 -> packed bf16x8 (RNE), one uint4
__device__ __forceinline__ uint4 cvt8(const float* src) {
  float4 v0 = *reinterpret_cast<const float4*>(src);
  float4 v1 = *reinterpret_cast<const float4*>(src + 4);
  uint4 w;
  w.x = cvt_pk_bf16(v0.x, v0.y);
  w.y = cvt_pk_bf16(v0.z, v0.w);
  w.z = cvt_pk_bf16(v1.x, v1.y);
  w.w = cvt_pk_bf16(v1.z, v1.w);
  return w;
}

// ---------------------------------------------------------------- GEMM (NT)
// out[m][o] = act( sum_k A[m][k] * W[o][k] + bias[o] (+ resid) )
// BMxBN tiles, BK=64, 4 waves (2x2), wave tile (BM/2)x(BN/2).
// 2-phase pipelined loop; one __syncthreads per K-step.
// AF32: A is float32, converted to bf16 during reg-staging.
// ACOMB: A is the attention split-K partial set (pacc,pl).
// RES: 0 none, 1 f32 residual, 2 bf16 residual (z=0 only under DUAL==2).
// DUAL: 1 = second independent problem on z; 2 = split-K halves on z.
// WF32: 1 = W is float32 (converted in staging; W/W2 params carry f32 ptrs
//       cast to ushort*); 2 = qkv 3-way select: bn0->W(f32 Wqd),
//       bn1->W2(f32 Wkd), bn>=2->wvf (f32 Wv, row offset (bn-2)*64).
template <int BM, int BN, int ACT, int OBF, int RES, int DUAL, int AF32,
          int ACOMB, int WF32>
__global__ __launch_bounds__(256)
void gemm_nt(const void* __restrict__ Araw, int lda,
             const unsigned short* __restrict__ W, int ldw,
             const float* __restrict__ bias, const float* __restrict__ bias2,
             int bsplit, const float* __restrict__ bias3, int bsplit2,
             const void* __restrict__ resid, void* __restrict__ outp,
             int K, int O,
             const void* A2, const unsigned short* W2,
             const float* biasB, void* outp2,
             const unsigned short* paccp, const float* plp,
             const float* wvf) {
  constexpr int MFW = BM / 32;  // m frags per wave
  constexpr int NFW = BN / 32;  // n frags per wave
  __shared__ __align__(16) unsigned short lA[2][BM * 64];
  __shared__ __align__(16) unsigned short lB[2][BN * 64];
  const int tid = threadIdx.x, lane = tid & 63, wid = tid >> 6;
  const int wr = wid >> 1, wc = wid & 1;
  const int l15 = lane & 15, lg = lane >> 4;
  const int bm = blockIdx.x, bn = blockIdx.y;

  const void* Ap = Araw;
  const unsigned short* Wp = W;
  const float* biasp = bias;
  void* outpp = outp;
  if (DUAL && blockIdx.z) {
    Ap = A2; Wp = W2; outpp = outp2;
    if (DUAL == 1) biasp = biasB;
  }

  auto stage = [&](int k0, int buf) {
#pragma unroll
    for (int it = 0; it < BM / 32; ++it) {  // A tile BMx64
      int c = it * 256 + tid;
      int row = c >> 3, cc = (c & 7) ^ (row & 7);
      if (ACOMB) {
        // fused attention combine: lA = (sum_c pacc[c]) / (sum_c pl[c])
        int g = k0 + cc * 8;          // global col 0..255 = h*32+d
        int grow = bm * BM + row;     // token row
        int b = grow >> 11, q = grow & 2047;
        int h = g >> 5, d = g & 31;
        size_t base = ((size_t)(b * 8 + h) * 2048 + q) * 32 + d;
        size_t lbase = (size_t)(b * 8 + h) * 2048 + q;
        float o0 = 0, o1 = 0, o2 = 0, o3 = 0, o4 = 0, o5 = 0, o6 = 0, o7 = 0;
        float L = 0.0f;
#pragma unroll
        for (int c2 = 0; c2 < KC; ++c2) {
          short8 a8 = *reinterpret_cast<const short8*>(
              paccp + (size_t)c2 * 2097152 + base);
          o0 += bf2f((unsigned short)a8[0]);
          o1 += bf2f((unsigned short)a8[1]);
          o2 += bf2f((unsigned short)a8[2]);
          o3 += bf2f((unsigned short)a8[3]);
          o4 += bf2f((unsigned short)a8[4]);
          o5 += bf2f((unsigned short)a8[5]);
          o6 += bf2f((unsigned short)a8[6]);
          o7 += bf2f((unsigned short)a8[7]);
          L += plp[(size_t)c2 * 65536 + lbase];
        }
        float inv = 1.0f / L;
        uint4 w;
        w.x = cvt_pk_bf16(o0 * inv, o1 * inv);
        w.y = cvt_pk_bf16(o2 * inv, o3 * inv);
        w.z = cvt_pk_bf16(o4 * inv, o5 * inv);
        w.w = cvt_pk_bf16(o6 * inv, o7 * inv);
        *reinterpret_cast<uint4*>(&lA[buf][c * 8]) = w;
      } else if (AF32) {
        const float* src =
            (const float*)Ap + (size_t)(bm * BM + row) * lda + k0 + cc * 8;
        *reinterpret_cast<uint4*>(&lA[buf][c * 8]) = cvt8(src);
      } else {
        gl_lds16((const unsigned short*)Ap +
                     (size_t)(bm * BM + row) * lda + k0 + cc * 8,
                 &lA[buf][c * 8]);
      }
    }
#pragma unroll
    for (int it = 0; it < BN / 32; ++it) {  // W tile BNx64
      int c = it * 256 + tid;
      int row = c >> 3, cc = (c & 7) ^ (row & 7);
      if (WF32 == 2) {
        const float* wsrc;
        int wrow;
        if (bn == 0) { wsrc = (const float*)W; wrow = row; }
        else if (bn == 1) { wsrc = (const float*)W2; wrow = row; }
        else { wsrc = wvf; wrow = (bn - 2) * 64 + row; }
        *reinterpret_cast<uint4*>(&lB[buf][c * 8]) =
            cvt8(wsrc + (size_t)wrow * ldw + k0 + cc * 8);
      } else if (WF32 == 1) {
        const float* wsrc = (const float*)Wp;
        *reinterpret_cast<uint4*>(&lB[buf][c * 8]) =
            cvt8(wsrc + (size_t)(bn * BN + row) * ldw + k0 + cc * 8);
      } else {
        gl_lds16(Wp + (size_t)(bn * BN + row) * ldw + k0 + cc * 8,
                 &lB[buf][c * 8]);
      }
    }
  };

  f32x4 acc[MFW][NFW];
#pragma unroll
  for (int i = 0; i < MFW; ++i)
#pragma unroll
    for (int j = 0; j < NFW; ++j) acc[i][j] = (f32x4)0.0f;

  const int T = K >> 6;
  stage(0, 0);
  __syncthreads();
  for (int t = 0; t < T; ++t) {
    const int cur = t & 1;
    if (t + 1 < T) stage((t + 1) << 6, cur ^ 1);
#pragma unroll
    for (int kk = 0; kk < 2; ++kk) {
      short8 a[MFW], b[NFW];
#pragma unroll
      for (int mf = 0; mf < MFW; ++mf) {
        int row = wr * (BM / 2) + mf * 16 + l15;
        a[mf] = *reinterpret_cast<const short8*>(
            &lA[cur][row * 64 + (((kk * 4 + lg) ^ (l15 & 7)) << 3)]);
      }
#pragma unroll
      for (int nf = 0; nf < NFW; ++nf) {
        int row = wc * (BN / 2) + nf * 16 + l15;
        b[nf] = *reinterpret_cast<const short8*>(
            &lB[cur][row * 64 + (((kk * 4 + lg) ^ (l15 & 7)) << 3)]);
      }
#pragma unroll
      for (int mf = 0; mf < MFW; ++mf)
#pragma unroll
        for (int nf = 0; nf < NFW; ++nf)
          acc[mf][nf] = __builtin_amdgcn_mfma_f32_16x16x32_bf16(
              a[mf], b[nf], acc[mf][nf], 0, 0, 0);
    }
    __syncthreads();
  }

  const bool zhalf = (DUAL == 2) && blockIdx.z;
#pragma unroll
  for (int mf = 0; mf < MFW; ++mf)
#pragma unroll
    for (int nf = 0; nf < NFW; ++nf) {
      int col = bn * BN + wc * (BN / 2) + nf * 16 + l15;
      float bv;
      if (zhalf) bv = 0.0f;
      else if (bias3 && col >= bsplit2) bv = bias3[col - bsplit2];
      else if (bias2 && col >= bsplit) bv = bias2[col - bsplit];
      else bv = biasp[col];
#pragma unroll
      for (int i = 0; i < 4; ++i) {
        int row = bm * BM + wr * (BM / 2) + mf * 16 + lg * 4 + i;
        float v = acc[mf][nf][i] + bv;
        if (ACT == 1) v = 0.5f * v * (1.0f + erff(v * 0.70710678118654752f));
        if (RES == 1 && !zhalf)
          v += ((const float*)resid)[(size_t)row * O + col];
        else if (RES == 2 && !zhalf)
          v += bf2f(((const unsigned short*)resid)[(size_t)row * O + col]);
        if (OBF)
          ((unsigned short*)outpp)[(size_t)row * O + col] = f2bf(v);
        else
          ((float*)outpp)[(size_t)row * O + col] = v;
      }
    }
}

// ---------------------------------------------------------------- attention
// Swapped-operand flash attention, FIXED-MAX softmax, zero-LDS P path
// (pi-permuted PV operands). KVB=128 processed as two 64-kv halves with one
// barrier per 128 kv. lK 16B-block XOR swizzle; lVt pi-permuted + 16B-block
// XOR swizzle; l via ones-row MFMA. LDS 32KB -> 5 blocks/CU.
__global__ __launch_bounds__(256)
void attn_kernel(const unsigned short* __restrict__ Qb,
                 const unsigned short* __restrict__ Kb,
                 const unsigned short* __restrict__ qv,  // V at col 128/384
                 unsigned short* __restrict__ pacc,  // [KC][32][2048][32] bf16
                 float* __restrict__ pl) {            // [KC][65536]
  __shared__ __align__(16) unsigned short lK[2][KVB * 32];   // swz [128][32]
  __shared__ __align__(16) unsigned short lVt[2][32 * KVB];  // permuted V^T
  const int tid = threadIdx.x, lane = tid & 63, wid = tid >> 6;
  const int l15 = lane & 15, lg = lane >> 4;
  const int bh = blockIdx.x, qt = blockIdx.y, kc = blockIdx.z;
  const int b = bh >> 3, h = bh & 7;
  const size_t headoff = (size_t)h * NDK;
  const int qbase = qt * 128 + wid * 32;
  const int kv0 = kc * (NS / KC);
  const float qscale = 0.25508686f;  // (1/sqrt(32)) * log2(e) -> log2 domain

  // Q fragments, pre-scaled into log2 domain
  short8 aq[2];
#pragma unroll
  for (int r = 0; r < 2; ++r) {
    short8 v = *reinterpret_cast<const short8*>(
        Qb + (size_t)(b * NS + qbase + r * 16 + l15) * ND + headoff + lg * 8);
#pragma unroll
    for (int j = 0; j < 8; ++j)
      v[j] = (short)f2bf(bf2f((unsigned short)v[j]) * qscale);
    aq[r] = v;
  }
  short8 ones8;
#pragma unroll
  for (int j = 0; j < 8; ++j) ones8[j] = (short)0x3F80;  // bf16 1.0

  // K staging: two 64-row halves; row=tid>>2 (+64), 16B-block pre-swizzled
  // by s(row)=(row>>1)&3 (same for row+64 since 64 ≡ 0 mod 4... (row>>1)&3
  // differs only via row; row+64 -> same s since 64>>1=32 ≡ 0 mod 4).
  const unsigned short* kptr =
      Kb + (size_t)(b * NS + kv0 + (tid >> 2)) * ND + headoff +
      (((tid & 3) ^ ((tid >> 3) & 3)) << 3);
  // V staging: lane covers d = vd0, vd0+1 and kv = vk0..vk0+3 in each half.
  const int vd0 = (tid & 15) * 2, vk0 = (tid >> 4) * 4;
  const unsigned short* vptr =
      qv + (size_t)(b * NS + kv0 + vk0) * QVLD + 128 + headoff + vd0;
  // pi-permuted position of the 4-aligned kv run within its half:
  const int vB16 = (vk0 >> 5) * 4 + ((vk0 >> 2) & 3);  // 16B block (pre-swz)
  const int vhalf8 = (vk0 >> 4) & 1;                   // 8B half within 16B
  const int vsw = (vd0 >> 1) & 7;
  const int vshort = (((vB16 ^ vsw) << 1) | vhalf8) * 4;  // short off in half

  auto writeV = [&](const unsigned* w, int buf, int hh) {
    unsigned lo0 = (w[0] & 0xffffu) | (w[1] << 16);
    unsigned lo1 = (w[2] & 0xffffu) | (w[3] << 16);
    unsigned hi0 = (w[0] >> 16) | (w[1] & 0xffff0000u);
    unsigned hi1 = (w[2] >> 16) | (w[3] & 0xffff0000u);
    int base = hh * 64 + vshort;
    *reinterpret_cast<uint2*>(&lVt[buf][vd0 * KVB + base]) =
        make_uint2(lo0, lo1);
    *reinterpret_cast<uint2*>(&lVt[buf][(vd0 + 1) * KVB + base]) =
        make_uint2(hi0, hi1);
  };
  auto stageK = [&](const unsigned short* kp, int buf) {
    gl_lds16(kp, &lK[buf][tid * 8]);
    gl_lds16(kp + (size_t)64 * ND, &lK[buf][(256 + tid) * 8]);
  };
  auto loadV = [&](const unsigned short* vp, unsigned* w) {
#pragma unroll
    for (int u = 0; u < 4; ++u) {
      w[u] = *reinterpret_cast<const unsigned*>(vp + (size_t)u * QVLD);
      w[4 + u] = *reinterpret_cast<const unsigned*>(
          vp + (size_t)(64 + u) * QVLD);
    }
  };

  f32x4 accT[2][2];  // [r][dt]: O^T fragment, col=q(l15), row=d(lg*4+i)
  f32x4 accL[2];     // ones-row MFMA accumulation -> l
#pragma unroll
  for (int r = 0; r < 2; ++r) {
    accL[r] = (f32x4)0.0f;
#pragma unroll
    for (int d = 0; d < 2; ++d) accT[r][d] = (f32x4)0.0f;
  }

  unsigned vr[8];
  stageK(kptr, 0);
  loadV(vptr, vr);
  writeV(vr, 0, 0);
  writeV(vr + 4, 0, 1);
  __syncthreads();

  for (int kt = 0; kt < KTILES; ++kt) {
    const int cur = kt & 1, nxt = cur ^ 1;
    const bool pf = (kt + 1 < KTILES);
    if (pf) {
      kptr += (size_t)KVB * ND;
      vptr += (size_t)KVB * QVLD;
      stageK(kptr, nxt);
      loadV(vptr, vr);
    }

#pragma unroll
    for (int hh = 0; hh < 2; ++hh) {
      // K fragments for this half: read once, reused for both r
      short8 bk[4];
#pragma unroll
      for (int t = 0; t < 4; ++t)
        bk[t] = *reinterpret_cast<const short8*>(
            &lK[cur][(hh * 64 + t * 16 + l15) * 32 +
                     ((lg ^ ((l15 >> 1) & 3)) << 3)]);

#pragma unroll
      for (int r = 0; r < 2; ++r) {
        // S^T tiles (log2 domain): lane holds q=l15, kv = t*16 + lg*4 + i
        f32x4 sT[4];
        __builtin_amdgcn_s_setprio(1);
#pragma unroll
        for (int t = 0; t < 4; ++t)
          sT[t] = __builtin_amdgcn_mfma_f32_16x16x32_bf16(
              bk[t], aq[r], (f32x4)0.0f, 0, 0, 0);
        __builtin_amdgcn_s_setprio(0);
        // P = exp2(S); pack to bf16 in registers (no LDS round-trip)
        unsigned wv[4][2];
#pragma unroll
        for (int t = 0; t < 4; ++t) {
          float p0 = __builtin_amdgcn_exp2f(sT[t][0]);
          float p1 = __builtin_amdgcn_exp2f(sT[t][1]);
          float p2 = __builtin_amdgcn_exp2f(sT[t][2]);
          float p3 = __builtin_amdgcn_exp2f(sT[t][3]);
          wv[t][0] = cvt_pk_bf16(p0, p1);
          wv[t][1] = cvt_pk_bf16(p2, p3);
        }
        // PV with pi-permuted operands: pa(kk) = own packed words
        __builtin_amdgcn_s_setprio(1);
#pragma unroll
        for (int kk = 0; kk < 2; ++kk) {
          union { uint4 u; short8 s; } pc;
          pc.u = make_uint4(wv[2 * kk][0], wv[2 * kk][1],
                            wv[2 * kk + 1][0], wv[2 * kk + 1][1]);
          short8 pa = pc.s;
          accL[r] = __builtin_amdgcn_mfma_f32_16x16x32_bf16(
              ones8, pa, accL[r], 0, 0, 0);
#pragma unroll
          for (int dt = 0; dt < 2; ++dt) {
            int B16r = (kk * 4 + lg) ^ ((l15 >> 1) & 7);
            short8 bv = *reinterpret_cast<const short8*>(
                &lVt[cur][(dt * 16 + l15) * KVB + hh * 64 + B16r * 8]);
            accT[r][dt] = __builtin_amdgcn_mfma_f32_16x16x32_bf16(
                bv, pa, accT[r][dt], 0, 0, 0);
          }
        }
        __builtin_amdgcn_s_setprio(0);
      }
    }

    if (pf) {
      writeV(vr, nxt, 0);
      writeV(vr + 4, nxt, 1);
    }
    __syncthreads();
  }

  // partial outputs: acc (unnormalized, packed u32) + l (from ones-MFMA)
#pragma unroll
  for (int r = 0; r < 2; ++r) {
    int qg = qbase + r * 16 + l15;
    size_t rowbase = ((size_t)kc * 65536 + (size_t)bh * NS + qg) * 32;
#pragma unroll
    for (int dt = 0; dt < 2; ++dt) {
      unsigned w0 = cvt_pk_bf16(accT[r][dt][0], accT[r][dt][1]);
      unsigned w1 = cvt_pk_bf16(accT[r][dt][2], accT[r][dt][3]);
      *reinterpret_cast<uint2*>(&pacc[rowbase + dt * 16 + lg * 4]) =
          make_uint2(w0, w1);
    }
  }
  if (lane < 16) {
#pragma unroll
    for (int r = 0; r < 2; ++r) {
      int qg = qbase + r * 16 + l15;
      pl[(size_t)kc * 65536 + (size_t)bh * NS + qg] = accL[r][0];
    }
  }
}

// ---------------------------------------------------------------- LN
// y = LayerNorm(a (+ b)) * g + be. Wave per row (D=256 = 64 lanes x 4).
__global__ __launch_bounds__(256)
void ln_res_kernel(const float* __restrict__ a, const float* bsrc,
                   const float* __restrict__ g, const float* __restrict__ be,
                   float* yf, unsigned short* yb) {
  int row = blockIdx.x * 4 + (threadIdx.x >> 6);
  int lane = threadIdx.x & 63;
  size_t off = (size_t)row * ND + lane * 4;
  float4 va = *reinterpret_cast<const float4*>(a + off);
  float v0 = va.x, v1 = va.y, v2 = va.z, v3 = va.w;
  if (bsrc) {
    float4 vb = *reinterpret_cast<const float4*>(bsrc + off);
    v0 += vb.x; v1 += vb.y; v2 += vb.z; v3 += vb.w;
  }
  float s = v0 + v1 + v2 + v3;
  float sq = v0 * v0 + v1 * v1 + v2 * v2 + v3 * v3;
#pragma unroll
  for (int o = 1; o < 64; o <<= 1) {
    s += __shfl_xor(s, o);
    sq += __shfl_xor(sq, o);
  }
  float mu = s * (1.0f / 256.0f);
  float var = sq * (1.0f / 256.0f) - mu * mu;
  float rs = rsqrtf(var + 1e-5f);
  float4 vg = *reinterpret_cast<const float4*>(g + lane * 4);
  float4 vbe = *reinterpret_cast<const float4*>(be + lane * 4);
  float o0 = (v0 - mu) * rs * vg.x + vbe.x;
  float o1 = (v1 - mu) * rs * vg.y + vbe.y;
  float o2 = (v2 - mu) * rs * vg.z + vbe.z;
  float o3 = (v3 - mu) * rs * vg.w + vbe.w;
  if (yf) *reinterpret_cast<float4*>(yf + off) = make_float4(o0, o1, o2, o3);
  if (yb) {
    ushort4 ob;
    ob.x = f2bf(o0); ob.y = f2bf(o1); ob.z = f2bf(o2); ob.w = f2bf(o3);
    *reinterpret_cast<ushort4*>(yb + off) = ob;
  }
}

// ---------------------------------------------------------------- launch
extern "C" void kernel_launch(void* const* d_in, const int* in_sizes, int n_in,
                              void* d_out, int out_size, void* d_ws,
                              size_t ws_size, hipStream_t stream) {
  (void)in_sizes; (void)n_in; (void)out_size; (void)ws_size;
  const float* x   = (const float*)d_in[0];
  const float* Wqd = (const float*)d_in[1];
  const float* bqd = (const float*)d_in[2];
  const float* Wqu = (const float*)d_in[3];
  const float* bqu = (const float*)d_in[4];
  const float* Wkd = (const float*)d_in[5];
  const float* bkd = (const float*)d_in[6];
  const float* Wku = (const float*)d_in[7];
  const float* bku = (const float*)d_in[8];
  const float* Wv  = (const float*)d_in[9];
  const float* bv  = (const float*)d_in[10];
  const float* Wo  = (const float*)d_in[11];
  const float* bo  = (const float*)d_in[12];
  const float* g1  = (const float*)d_in[13];
  const float* be1 = (const float*)d_in[14];
  const float* Wf1 = (const float*)d_in[15];
  const float* bf1 = (const float*)d_in[16];
  const float* Wf2 = (const float*)d_in[17];
  const float* bf2 = (const float*)d_in[18];
  const float* g2  = (const float*)d_in[19];
  const float* be2 = (const float*)d_in[20];

  char* p = (char*)d_ws;
  auto alloc = [&](size_t bytes) {
    char* r = p;
    p += (bytes + 255) & ~(size_t)255;
    return r;
  };
  unsigned short* qv  = (unsigned short*)alloc((size_t)NROWS * QVLD * 2);
  unsigned short* Qb  = (unsigned short*)alloc((size_t)NROWS * ND * 2);
  unsigned short* Kb  = (unsigned short*)alloc((size_t)NROWS * ND * 2);
  float*          pl  = (float*)alloc((size_t)KC * 65536 * 4);
  unsigned short* y1b = (unsigned short*)alloc((size_t)NROWS * ND * 2);
  float*          ao2 = (float*)alloc((size_t)NROWS * ND * 4);
  unsigned short* hb  = (unsigned short*)alloc((size_t)NROWS * NDFF * 2);
  float* ao = (float*)d_out;  // d_out doubles as f32 scratch

  // split-K pacc aliases hb (dead until FF1 writes; Wo consumes pacc first)
  unsigned short* pacc = hb;

  // fused Q-down + K-down + V from f32 x (AF32) and f32 weights (WF32=2:
  // bn0->Wqd, bn1->Wkd, bn>=2->Wv)
  gemm_nt<64, 64, 0, 1, 0, 0, 1, 0, 2><<<dim3(128, 6), 256, 0, stream>>>(
      x, 256, (const unsigned short*)Wqd, 256, bqd, bkd, 64, bv, 128,
      nullptr, qv, 256, QVLD,
      nullptr, (const unsigned short*)Wkd, nullptr, nullptr,
      nullptr, nullptr, Wv);
  // up-projections: Q (z=0), K (z=1) in one dual launch; W f32 in-staging
  gemm_nt<64, 64, 0, 1, 0, 1, 0, 0, 1><<<dim3(128, 4, 2), 256, 0, stream>>>(
      qv, QVLD, (const unsigned short*)Wqu, 64, bqu, nullptr, 0, nullptr, 0,
      nullptr, Qb, 64, 256,
      qv + 64, (const unsigned short*)Wku, bku, Kb, nullptr, nullptr, nullptr);

  attn_kernel<<<dim3(NB * NH, NS / 128, KC), 256, 0, stream>>>(
      Qb, Kb, qv, pacc, pl);

  // out proj with FUSED split-K combine in A-staging + residual(x) -> ao,
  // then LN1 (bf16 output only); Wo f32 in-staging
  gemm_nt<64, 64, 0, 0, 1, 0, 0, 1, 1><<<dim3(128, 4), 256, 0, stream>>>(
      nullptr, 256, (const unsigned short*)Wo, 256, bo, nullptr, 0, nullptr,
      0, x, ao, 256, 256,
      nullptr, nullptr, nullptr, nullptr, pacc, pl, nullptr);
  ln_res_kernel<<<NROWS / 4, 256, 0, stream>>>(ao, nullptr, g1, be1,
                                               nullptr, y1b);

  // FFN: FF1+GELU (128x128 tile, Wf1 f32 in-staging); FF2 split-K over z
  // (K=512 each half, Wf2 f32; z0: +bias +bf16 residual -> ao, z1 -> ao2);
  // LN2 sums ao+ao2
  gemm_nt<128, 128, 1, 1, 0, 0, 0, 0, 1><<<dim3(64, 8), 256, 0, stream>>>(
      y1b, 256, (const unsigned short*)Wf1, 256, bf1, nullptr, 0, nullptr, 0,
      nullptr, hb, 256, NDFF,
      nullptr, nullptr, nullptr, nullptr, nullptr, nullptr, nullptr);
  gemm_nt<64, 64, 0, 0, 2, 2, 0, 0, 1><<<dim3(128, 4, 2), 256, 0, stream>>>(
      hb, 1024, (const unsigned short*)Wf2, 1024, bf2, nullptr, 0, nullptr, 0,
      y1b, ao, 512, 256,
      hb + 512, (const unsigned short*)(Wf2 + 512), nullptr, ao2,
      nullptr, nullptr, nullptr);
  ln_res_kernel<<<NROWS / 4, 256, 0, stream>>>(ao, ao2, g2, be2,
                                               (float*)d_out, nullptr);
}

// Round 17
// 103.514 us; speedup vs baseline: 1.0164x; 1.0164x over previous
//
#include <hip/hip_runtime.h>
#include <hip/hip_bf16.h>
#include <math.h>

#define NB 4
#define NS 2048
#define ND 256
#define NH 8
#define NDK 32
#define NDFF 1024
#define NROWS (NB * NS)   // 8192
#define KC 4              // split-K chunks in attention
#define KVB 128
#define KTILES (NS / KC / KVB)  // 4
#define QVLD 384          // fused qkv output row stride

using short8 = __attribute__((ext_vector_type(8))) short;
using f32x4  = __attribute__((ext_vector_type(4))) float;

__device__ __forceinline__ unsigned short f2bf(float f) {
  union { float f; unsigned u; } v; v.f = f;
  unsigned r = v.u + 0x7fffu + ((v.u >> 16) & 1u);
  return (unsigned short)(r >> 16);
}
__device__ __forceinline__ float bf2f(unsigned short u) {
  union { unsigned u; float f; } v; v.u = ((unsigned)u) << 16;
  return v.f;
}
__device__ __forceinline__ unsigned cvt_pk_bf16(float lo, float hi) {
  unsigned r;
  asm("v_cvt_pk_bf16_f32 %0, %1, %2" : "=v"(r) : "v"(lo), "v"(hi));
  return r;
}
// async global->LDS, 16B per lane; dest must be wave-uniform base + lane*16
__device__ __forceinline__ void gl_lds16(const void* g, void* l) {
  __builtin_amdgcn_global_load_lds(
      (const __attribute__((address_space(1))) unsigned int*)g,
      (__attribute__((address_space(3))) unsigned int*)l, 16, 0, 0);
}

// ------------------------------------------------------------- batched cvt
__global__ void cvt_batch(const float* s0, const float* s1, const float* s2,
                          const float* s3, const float* s4, const float* s5,
                          const float* s6, const float* s7,
                          unsigned short* d0, unsigned short* d1,
                          unsigned short* d2, unsigned short* d3,
                          unsigned short* d4, unsigned short* d5,
                          unsigned short* d6, unsigned short* d7,
                          int n0, int n1, int n2, int n3, int n4, int n5,
                          int n6, int n7) {
  const float* s; unsigned short* d; int n;
  switch (blockIdx.y) {
    case 0: s = s0; d = d0; n = n0; break;
    case 1: s = s1; d = d1; n = n1; break;
    case 2: s = s2; d = d2; n = n2; break;
    case 3: s = s3; d = d3; n = n3; break;
    case 4: s = s4; d = d4; n = n4; break;
    case 5: s = s5; d = d5; n = n5; break;
    case 6: s = s6; d = d6; n = n6; break;
    default: s = s7; d = d7; n = n7; break;
  }
  for (int i = (blockIdx.x * 256 + threadIdx.x) * 4; i < n; i += 256 * 256 * 4) {
    float4 v = *reinterpret_cast<const float4*>(s + i);
    ushort4 o;
    o.x = f2bf(v.x); o.y = f2bf(v.y); o.z = f2bf(v.z); o.w = f2bf(v.w);
    *reinterpret_cast<ushort4*>(d + i) = o;
  }
}

// ---------------------------------------------------------------- GEMM (NT)
// out[m][o] = act( sum_k A[m][k] * W[o][k] + bias[o] (+ resid) )
// BMxBN tiles, BK=64, 4 waves (2x2), wave tile (BM/2)x(BN/2).
// 2-phase pipelined loop; one __syncthreads per K-step.
// AF32: A is float32, converted to bf16 during reg-staging.
// ACOMB: A is the attention split-K partial set (pacc,pl).
// RES: 0 none, 1 f32 residual, 2 bf16 residual (z=0 only under DUAL==2).
// DUAL: 1 = second independent problem on z; 2 = split-K halves on z.
template <int BM, int BN, int ACT, int OBF, int RES, int DUAL, int AF32,
          int ACOMB>
__global__ __launch_bounds__(256)
void gemm_nt(const void* __restrict__ Araw, int lda,
             const unsigned short* __restrict__ W, int ldw,
             const float* __restrict__ bias, const float* __restrict__ bias2,
             int bsplit, const float* __restrict__ bias3, int bsplit2,
             const void* __restrict__ resid, void* __restrict__ outp,
             int K, int O,
             const void* A2, const unsigned short* W2,
             const float* biasB, void* outp2,
             const unsigned short* paccp, const float* plp) {
  constexpr int MFW = BM / 32;  // m frags per wave
  constexpr int NFW = BN / 32;  // n frags per wave
  __shared__ __align__(16) unsigned short lA[2][BM * 64];
  __shared__ __align__(16) unsigned short lB[2][BN * 64];
  const int tid = threadIdx.x, lane = tid & 63, wid = tid >> 6;
  const int wr = wid >> 1, wc = wid & 1;
  const int l15 = lane & 15, lg = lane >> 4;
  const int bm = blockIdx.x, bn = blockIdx.y;

  const void* Ap = Araw;
  const unsigned short* Wp = W;
  const float* biasp = bias;
  void* outpp = outp;
  if (DUAL && blockIdx.z) {
    Ap = A2; Wp = W2; outpp = outp2;
    if (DUAL == 1) biasp = biasB;
  }

  auto stage = [&](int k0, int buf) {
#pragma unroll
    for (int it = 0; it < BM / 32; ++it) {  // A tile BMx64
      int c = it * 256 + tid;
      int row = c >> 3, cc = (c & 7) ^ (row & 7);
      if (ACOMB) {
        // fused attention combine: lA = (sum_c pacc[c]) / (sum_c pl[c])
        int g = k0 + cc * 8;          // global col 0..255 = h*32+d
        int grow = bm * BM + row;     // token row
        int b = grow >> 11, q = grow & 2047;
        int h = g >> 5, d = g & 31;
        size_t base = ((size_t)(b * 8 + h) * 2048 + q) * 32 + d;
        size_t lbase = (size_t)(b * 8 + h) * 2048 + q;
        float o0 = 0, o1 = 0, o2 = 0, o3 = 0, o4 = 0, o5 = 0, o6 = 0, o7 = 0;
        float L = 0.0f;
#pragma unroll
        for (int c2 = 0; c2 < KC; ++c2) {
          short8 a8 = *reinterpret_cast<const short8*>(
              paccp + (size_t)c2 * 2097152 + base);
          o0 += bf2f((unsigned short)a8[0]);
          o1 += bf2f((unsigned short)a8[1]);
          o2 += bf2f((unsigned short)a8[2]);
          o3 += bf2f((unsigned short)a8[3]);
          o4 += bf2f((unsigned short)a8[4]);
          o5 += bf2f((unsigned short)a8[5]);
          o6 += bf2f((unsigned short)a8[6]);
          o7 += bf2f((unsigned short)a8[7]);
          L += plp[(size_t)c2 * 65536 + lbase];
        }
        float inv = 1.0f / L;
        uint4 w;
        w.x = cvt_pk_bf16(o0 * inv, o1 * inv);
        w.y = cvt_pk_bf16(o2 * inv, o3 * inv);
        w.z = cvt_pk_bf16(o4 * inv, o5 * inv);
        w.w = cvt_pk_bf16(o6 * inv, o7 * inv);
        *reinterpret_cast<uint4*>(&lA[buf][c * 8]) = w;
      } else if (AF32) {
        const float* src =
            (const float*)Ap + (size_t)(bm * BM + row) * lda + k0 + cc * 8;
        float4 v0 = *reinterpret_cast<const float4*>(src);
        float4 v1 = *reinterpret_cast<const float4*>(src + 4);
        uint4 w;
        w.x = cvt_pk_bf16(v0.x, v0.y);
        w.y = cvt_pk_bf16(v0.z, v0.w);
        w.z = cvt_pk_bf16(v1.x, v1.y);
        w.w = cvt_pk_bf16(v1.z, v1.w);
        *reinterpret_cast<uint4*>(&lA[buf][c * 8]) = w;
      } else {
        gl_lds16((const unsigned short*)Ap +
                     (size_t)(bm * BM + row) * lda + k0 + cc * 8,
                 &lA[buf][c * 8]);
      }
    }
#pragma unroll
    for (int it = 0; it < BN / 32; ++it) {  // W tile BNx64
      int c = it * 256 + tid;
      int row = c >> 3, cc = (c & 7) ^ (row & 7);
      gl_lds16(Wp + (size_t)(bn * BN + row) * ldw + k0 + cc * 8,
               &lB[buf][c * 8]);
    }
  };

  f32x4 acc[MFW][NFW];
#pragma unroll
  for (int i = 0; i < MFW; ++i)
#pragma unroll
    for (int j = 0; j < NFW; ++j) acc[i][j] = (f32x4)0.0f;

  const int T = K >> 6;
  stage(0, 0);
  __syncthreads();
  for (int t = 0; t < T; ++t) {
    const int cur = t & 1;
    if (t + 1 < T) stage((t + 1) << 6, cur ^ 1);
#pragma unroll
    for (int kk = 0; kk < 2; ++kk) {
      short8 a[MFW], b[NFW];
#pragma unroll
      for (int mf = 0; mf < MFW; ++mf) {
        int row = wr * (BM / 2) + mf * 16 + l15;
        a[mf] = *reinterpret_cast<const short8*>(
            &lA[cur][row * 64 + (((kk * 4 + lg) ^ (l15 & 7)) << 3)]);
      }
#pragma unroll
      for (int nf = 0; nf < NFW; ++nf) {
        int row = wc * (BN / 2) + nf * 16 + l15;
        b[nf] = *reinterpret_cast<const short8*>(
            &lB[cur][row * 64 + (((kk * 4 + lg) ^ (l15 & 7)) << 3)]);
      }
#pragma unroll
      for (int mf = 0; mf < MFW; ++mf)
#pragma unroll
        for (int nf = 0; nf < NFW; ++nf)
          acc[mf][nf] = __builtin_amdgcn_mfma_f32_16x16x32_bf16(
              a[mf], b[nf], acc[mf][nf], 0, 0, 0);
    }
    __syncthreads();
  }

  const bool zhalf = (DUAL == 2) && blockIdx.z;
#pragma unroll
  for (int mf = 0; mf < MFW; ++mf)
#pragma unroll
    for (int nf = 0; nf < NFW; ++nf) {
      int col = bn * BN + wc * (BN / 2) + nf * 16 + l15;
      float bv;
      if (zhalf) bv = 0.0f;
      else if (bias3 && col >= bsplit2) bv = bias3[col - bsplit2];
      else if (bias2 && col >= bsplit) bv = bias2[col - bsplit];
      else bv = biasp[col];
#pragma unroll
      for (int i = 0; i < 4; ++i) {
        int row = bm * BM + wr * (BM / 2) + mf * 16 + lg * 4 + i;
        float v = acc[mf][nf][i] + bv;
        if (ACT == 1) v = 0.5f * v * (1.0f + erff(v * 0.70710678118654752f));
        if (RES == 1 && !zhalf)
          v += ((const float*)resid)[(size_t)row * O + col];
        else if (RES == 2 && !zhalf)
          v += bf2f(((const unsigned short*)resid)[(size_t)row * O + col]);
        if (OBF)
          ((unsigned short*)outpp)[(size_t)row * O + col] = f2bf(v);
        else
          ((float*)outpp)[(size_t)row * O + col] = v;
      }
    }
}

// ---------------------------------------------------------------- attention
// Swapped-operand flash attention, FIXED-MAX softmax, zero-LDS P path
// (pi-permuted PV operands). KVB=128 processed as two 64-kv halves with one
// barrier per 128 kv. lK 16B-block XOR swizzle; lVt pi-permuted + 16B-block
// XOR swizzle; l via ones-row MFMA. LDS 32KB -> 5 blocks/CU.
__global__ __launch_bounds__(256)
void attn_kernel(const unsigned short* __restrict__ Qb,
                 const unsigned short* __restrict__ Kb,
                 const unsigned short* __restrict__ qv,  // V at col 128/384
                 unsigned short* __restrict__ pacc,  // [KC][32][2048][32] bf16
                 float* __restrict__ pl) {            // [KC][65536]
  __shared__ __align__(16) unsigned short lK[2][KVB * 32];   // swz [128][32]
  __shared__ __align__(16) unsigned short lVt[2][32 * KVB];  // permuted V^T
  const int tid = threadIdx.x, lane = tid & 63, wid = tid >> 6;
  const int l15 = lane & 15, lg = lane >> 4;
  const int bh = blockIdx.x, qt = blockIdx.y, kc = blockIdx.z;
  const int b = bh >> 3, h = bh & 7;
  const size_t headoff = (size_t)h * NDK;
  const int qbase = qt * 128 + wid * 32;
  const int kv0 = kc * (NS / KC);
  const float qscale = 0.25508686f;  // (1/sqrt(32)) * log2(e) -> log2 domain

  // Q fragments, pre-scaled into log2 domain
  short8 aq[2];
#pragma unroll
  for (int r = 0; r < 2; ++r) {
    short8 v = *reinterpret_cast<const short8*>(
        Qb + (size_t)(b * NS + qbase + r * 16 + l15) * ND + headoff + lg * 8);
#pragma unroll
    for (int j = 0; j < 8; ++j)
      v[j] = (short)f2bf(bf2f((unsigned short)v[j]) * qscale);
    aq[r] = v;
  }
  short8 ones8;
#pragma unroll
  for (int j = 0; j < 8; ++j) ones8[j] = (short)0x3F80;  // bf16 1.0

  // K staging: two 64-row halves; row=tid>>2 (+64), 16B-block pre-swizzled
  // by s(row)=(row>>1)&3.
  const unsigned short* kptr =
      Kb + (size_t)(b * NS + kv0 + (tid >> 2)) * ND + headoff +
      (((tid & 3) ^ ((tid >> 3) & 3)) << 3);
  // V staging: lane covers d = vd0, vd0+1 and kv = vk0..vk0+3 in each half.
  const int vd0 = (tid & 15) * 2, vk0 = (tid >> 4) * 4;
  const unsigned short* vptr =
      qv + (size_t)(b * NS + kv0 + vk0) * QVLD + 128 + headoff + vd0;
  // pi-permuted position of the 4-aligned kv run within its half:
  const int vB16 = (vk0 >> 5) * 4 + ((vk0 >> 2) & 3);  // 16B block (pre-swz)
  const int vhalf8 = (vk0 >> 4) & 1;                   // 8B half within 16B
  const int vsw = (vd0 >> 1) & 7;
  const int vshort = (((vB16 ^ vsw) << 1) | vhalf8) * 4;  // short off in half

  auto writeV = [&](const unsigned* w, int buf, int hh) {
    unsigned lo0 = (w[0] & 0xffffu) | (w[1] << 16);
    unsigned lo1 = (w[2] & 0xffffu) | (w[3] << 16);
    unsigned hi0 = (w[0] >> 16) | (w[1] & 0xffff0000u);
    unsigned hi1 = (w[2] >> 16) | (w[3] & 0xffff0000u);
    int base = hh * 64 + vshort;
    *reinterpret_cast<uint2*>(&lVt[buf][vd0 * KVB + base]) =
        make_uint2(lo0, lo1);
    *reinterpret_cast<uint2*>(&lVt[buf][(vd0 + 1) * KVB + base]) =
        make_uint2(hi0, hi1);
  };
  auto stageK = [&](const unsigned short* kp, int buf) {
    gl_lds16(kp, &lK[buf][tid * 8]);
    gl_lds16(kp + (size_t)64 * ND, &lK[buf][(256 + tid) * 8]);
  };
  auto loadV = [&](const unsigned short* vp, unsigned* w) {
#pragma unroll
    for (int u = 0; u < 4; ++u) {
      w[u] = *reinterpret_cast<const unsigned*>(vp + (size_t)u * QVLD);
      w[4 + u] = *reinterpret_cast<const unsigned*>(
          vp + (size_t)(64 + u) * QVLD);
    }
  };

  f32x4 accT[2][2];  // [r][dt]: O^T fragment, col=q(l15), row=d(lg*4+i)
  f32x4 accL[2];     // ones-row MFMA accumulation -> l
#pragma unroll
  for (int r = 0; r < 2; ++r) {
    accL[r] = (f32x4)0.0f;
#pragma unroll
    for (int d = 0; d < 2; ++d) accT[r][d] = (f32x4)0.0f;
  }

  unsigned vr[8];
  stageK(kptr, 0);
  loadV(vptr, vr);
  writeV(vr, 0, 0);
  writeV(vr + 4, 0, 1);
  __syncthreads();

  for (int kt = 0; kt < KTILES; ++kt) {
    const int cur = kt & 1, nxt = cur ^ 1;
    const bool pf = (kt + 1 < KTILES);
    if (pf) {
      kptr += (size_t)KVB * ND;
      vptr += (size_t)KVB * QVLD;
      stageK(kptr, nxt);
      loadV(vptr, vr);
    }

#pragma unroll
    for (int hh = 0; hh < 2; ++hh) {
      // K fragments for this half: read once, reused for both r
      short8 bk[4];
#pragma unroll
      for (int t = 0; t < 4; ++t)
        bk[t] = *reinterpret_cast<const short8*>(
            &lK[cur][(hh * 64 + t * 16 + l15) * 32 +
                     ((lg ^ ((l15 >> 1) & 3)) << 3)]);

#pragma unroll
      for (int r = 0; r < 2; ++r) {
        // S^T tiles (log2 domain): lane holds q=l15, kv = t*16 + lg*4 + i
        f32x4 sT[4];
        __builtin_amdgcn_s_setprio(1);
#pragma unroll
        for (int t = 0; t < 4; ++t)
          sT[t] = __builtin_amdgcn_mfma_f32_16x16x32_bf16(
              bk[t], aq[r], (f32x4)0.0f, 0, 0, 0);
        __builtin_amdgcn_s_setprio(0);
        // P = exp2(S); pack to bf16 in registers (no LDS round-trip)
        unsigned wv[4][2];
#pragma unroll
        for (int t = 0; t < 4; ++t) {
          float p0 = __builtin_amdgcn_exp2f(sT[t][0]);
          float p1 = __builtin_amdgcn_exp2f(sT[t][1]);
          float p2 = __builtin_amdgcn_exp2f(sT[t][2]);
          float p3 = __builtin_amdgcn_exp2f(sT[t][3]);
          wv[t][0] = cvt_pk_bf16(p0, p1);
          wv[t][1] = cvt_pk_bf16(p2, p3);
        }
        // PV with pi-permuted operands: pa(kk) = own packed words
        __builtin_amdgcn_s_setprio(1);
#pragma unroll
        for (int kk = 0; kk < 2; ++kk) {
          union { uint4 u; short8 s; } pc;
          pc.u = make_uint4(wv[2 * kk][0], wv[2 * kk][1],
                            wv[2 * kk + 1][0], wv[2 * kk + 1][1]);
          short8 pa = pc.s;
          accL[r] = __builtin_amdgcn_mfma_f32_16x16x32_bf16(
              ones8, pa, accL[r], 0, 0, 0);
#pragma unroll
          for (int dt = 0; dt < 2; ++dt) {
            int B16r = (kk * 4 + lg) ^ ((l15 >> 1) & 7);
            short8 bv = *reinterpret_cast<const short8*>(
                &lVt[cur][(dt * 16 + l15) * KVB + hh * 64 + B16r * 8]);
            accT[r][dt] = __builtin_amdgcn_mfma_f32_16x16x32_bf16(
                bv, pa, accT[r][dt], 0, 0, 0);
          }
        }
        __builtin_amdgcn_s_setprio(0);
      }
    }

    if (pf) {
      writeV(vr, nxt, 0);
      writeV(vr + 4, nxt, 1);
    }
    __syncthreads();
  }

  // partial outputs: acc (unnormalized, packed u32) + l (from ones-MFMA)
#pragma unroll
  for (int r = 0; r < 2; ++r) {
    int qg = qbase + r * 16 + l15;
    size_t rowbase = ((size_t)kc * 65536 + (size_t)bh * NS + qg) * 32;
#pragma unroll
    for (int dt = 0; dt < 2; ++dt) {
      unsigned w0 = cvt_pk_bf16(accT[r][dt][0], accT[r][dt][1]);
      unsigned w1 = cvt_pk_bf16(accT[r][dt][2], accT[r][dt][3]);
      *reinterpret_cast<uint2*>(&pacc[rowbase + dt * 16 + lg * 4]) =
          make_uint2(w0, w1);
    }
  }
  if (lane < 16) {
#pragma unroll
    for (int r = 0; r < 2; ++r) {
      int qg = qbase + r * 16 + l15;
      pl[(size_t)kc * 65536 + (size_t)bh * NS + qg] = accL[r][0];
    }
  }
}

// ---------------------------------------------------------------- LN
// y = LayerNorm(a (+ b)) * g + be. Wave per row (D=256 = 64 lanes x 4).
__global__ __launch_bounds__(256)
void ln_res_kernel(const float* __restrict__ a, const float* bsrc,
                   const float* __restrict__ g, const float* __restrict__ be,
                   float* yf, unsigned short* yb) {
  int row = blockIdx.x * 4 + (threadIdx.x >> 6);
  int lane = threadIdx.x & 63;
  size_t off = (size_t)row * ND + lane * 4;
  float4 va = *reinterpret_cast<const float4*>(a + off);
  float v0 = va.x, v1 = va.y, v2 = va.z, v3 = va.w;
  if (bsrc) {
    float4 vb = *reinterpret_cast<const float4*>(bsrc + off);
    v0 += vb.x; v1 += vb.y; v2 += vb.z; v3 += vb.w;
  }
  float s = v0 + v1 + v2 + v3;
  float sq = v0 * v0 + v1 * v1 + v2 * v2 + v3 * v3;
#pragma unroll
  for (int o = 1; o < 64; o <<= 1) {
    s += __shfl_xor(s, o);
    sq += __shfl_xor(sq, o);
  }
  float mu = s * (1.0f / 256.0f);
  float var = sq * (1.0f / 256.0f) - mu * mu;
  float rs = rsqrtf(var + 1e-5f);
  float4 vg = *reinterpret_cast<const float4*>(g + lane * 4);
  float4 vbe = *reinterpret_cast<const float4*>(be + lane * 4);
  float o0 = (v0 - mu) * rs * vg.x + vbe.x;
  float o1 = (v1 - mu) * rs * vg.y + vbe.y;
  float o2 = (v2 - mu) * rs * vg.z + vbe.z;
  float o3 = (v3 - mu) * rs * vg.w + vbe.w;
  if (yf) *reinterpret_cast<float4*>(yf + off) = make_float4(o0, o1, o2, o3);
  if (yb) {
    ushort4 ob;
    ob.x = f2bf(o0); ob.y = f2bf(o1); ob.z = f2bf(o2); ob.w = f2bf(o3);
    *reinterpret_cast<ushort4*>(yb + off) = ob;
  }
}

// ---------------------------------------------------------------- launch
extern "C" void kernel_launch(void* const* d_in, const int* in_sizes, int n_in,
                              void* d_out, int out_size, void* d_ws,
                              size_t ws_size, hipStream_t stream) {
  (void)in_sizes; (void)n_in; (void)out_size; (void)ws_size;
  const float* x   = (const float*)d_in[0];
  const float* Wqd = (const float*)d_in[1];
  const float* bqd = (const float*)d_in[2];
  const float* Wqu = (const float*)d_in[3];
  const float* bqu = (const float*)d_in[4];
  const float* Wkd = (const float*)d_in[5];
  const float* bkd = (const float*)d_in[6];
  const float* Wku = (const float*)d_in[7];
  const float* bku = (const float*)d_in[8];
  const float* Wv  = (const float*)d_in[9];
  const float* bv  = (const float*)d_in[10];
  const float* Wo  = (const float*)d_in[11];
  const float* bo  = (const float*)d_in[12];
  const float* g1  = (const float*)d_in[13];
  const float* be1 = (const float*)d_in[14];
  const float* Wf1 = (const float*)d_in[15];
  const float* bf1 = (const float*)d_in[16];
  const float* Wf2 = (const float*)d_in[17];
  const float* bf2 = (const float*)d_in[18];
  const float* g2  = (const float*)d_in[19];
  const float* be2 = (const float*)d_in[20];

  char* p = (char*)d_ws;
  auto alloc = [&](size_t bytes) {
    char* r = p;
    p += (bytes + 255) & ~(size_t)255;
    return r;
  };
  unsigned short* wqkv = (unsigned short*)alloc(384 * 256 * 2);  // qd|kd|v
  unsigned short* wqu  = (unsigned short*)alloc(256 * 64 * 2);
  unsigned short* wku  = (unsigned short*)alloc(256 * 64 * 2);
  unsigned short* wo   = (unsigned short*)alloc(256 * 256 * 2);
  unsigned short* wf1  = (unsigned short*)alloc(1024 * 256 * 2);
  unsigned short* wf2  = (unsigned short*)alloc(256 * 1024 * 2);
  unsigned short* qv   = (unsigned short*)alloc((size_t)NROWS * QVLD * 2);
  unsigned short* Qb   = (unsigned short*)alloc((size_t)NROWS * ND * 2);
  unsigned short* Kb   = (unsigned short*)alloc((size_t)NROWS * ND * 2);
  float*          pl   = (float*)alloc((size_t)KC * 65536 * 4);
  unsigned short* y1b  = (unsigned short*)alloc((size_t)NROWS * ND * 2);
  float*          ao2  = (float*)alloc((size_t)NROWS * ND * 4);
  unsigned short* hb   = (unsigned short*)alloc((size_t)NROWS * NDFF * 2);
  float* ao = (float*)d_out;  // d_out doubles as f32 scratch

  // split-K pacc aliases hb (dead until FF1 writes; Wo consumes pacc first)
  unsigned short* pacc = hb;

  cvt_batch<<<dim3(256, 8), 256, 0, stream>>>(
      Wqd, Wkd, Wqu, Wku, Wv, Wo, Wf1, Wf2,
      wqkv, wqkv + 64 * 256, wqu, wku, wqkv + 128 * 256, wo, wf1, wf2,
      64 * 256, 64 * 256, 256 * 64, 256 * 64, 256 * 256,
      256 * 256, 1024 * 256, 256 * 1024);

  // fused Q-down + K-down + V from f32 x (AF32 reg-staging converts inline)
  gemm_nt<64, 64, 0, 1, 0, 0, 1, 0><<<dim3(128, 6), 256, 0, stream>>>(
      x, 256, wqkv, 256, bqd, bkd, 64, bv, 128, nullptr, qv, 256, QVLD,
      nullptr, nullptr, nullptr, nullptr, nullptr, nullptr);
  // up-projections: Q (z=0), K (z=1) in one dual launch
  gemm_nt<64, 64, 0, 1, 0, 1, 0, 0><<<dim3(128, 4, 2), 256, 0, stream>>>(
      qv, QVLD, wqu, 64, bqu, nullptr, 0, nullptr, 0, nullptr, Qb, 64, 256,
      qv + 64, wku, bku, Kb, nullptr, nullptr);

  attn_kernel<<<dim3(NB * NH, NS / 128, KC), 256, 0, stream>>>(
      Qb, Kb, qv, pacc, pl);

  // out proj with FUSED split-K combine in A-staging + residual(x) -> ao,
  // then LN1 (bf16 output only)
  gemm_nt<64, 64, 0, 0, 1, 0, 0, 1><<<dim3(128, 4), 256, 0, stream>>>(
      nullptr, 256, wo, 256, bo, nullptr, 0, nullptr, 0, x, ao, 256, 256,
      nullptr, nullptr, nullptr, nullptr, pacc, pl);
  ln_res_kernel<<<NROWS / 4, 256, 0, stream>>>(ao, nullptr, g1, be1,
                                               nullptr, y1b);

  // FFN: FF1+GELU (128x128 tile); FF2 split-K over z (K=512 each half,
  // z0: +bias +bf16 residual -> ao, z1: bare -> ao2); LN2 sums ao+ao2
  gemm_nt<128, 128, 1, 1, 0, 0, 0, 0><<<dim3(64, 8), 256, 0, stream>>>(
      y1b, 256, wf1, 256, bf1, nullptr, 0, nullptr, 0, nullptr, hb, 256, NDFF,
      nullptr, nullptr, nullptr, nullptr, nullptr, nullptr);
  gemm_nt<64, 64, 0, 0, 2, 2, 0, 0><<<dim3(128, 4, 2), 256, 0, stream>>>(
      hb, 1024, wf2, 1024, bf2, nullptr, 0, nullptr, 0, y1b, ao, 512, 256,
      hb + 512, wf2 + 512, nullptr, ao2, nullptr, nullptr);
  ln_res_kernel<<<NROWS / 4, 256, 0, stream>>>(ao, ao2, g2, be2,
                                               (float*)d_out, nullptr);
}